// Round 1
// baseline (321.250 us; speedup 1.0000x reference)
//
#include <hip/hip_runtime.h>

#define LBL 5
#define START_T 3
#define END_T 4

__global__ __launch_bounds__(64) void crf_scores_kernel(
    const float* __restrict__ scores,   // [B,S,L]
    const int*   __restrict__ lens,     // [B]
    const int*   __restrict__ tags,     // [B,S]
    const float* __restrict__ trans,    // [L,L]
    float* __restrict__ out,            // [2] = {unlabeled, labeled}
    int B, int S)
{
    __shared__ float sT[LBL * LBL];
    int tid = threadIdx.x;
    if (tid < LBL * LBL) sT[tid] = trans[tid];
    __syncthreads();

    // exp(T) in registers (constant across t)
    float E[LBL][LBL];
    #pragma unroll
    for (int i = 0; i < LBL; ++i)
        #pragma unroll
        for (int j = 0; j < LBL; ++j)
            E[i][j] = __expf(sT[i * LBL + j]);

    int b = blockIdx.x * blockDim.x + tid;
    float unl = 0.0f, lab = 0.0f;

    if (b < B) {
        int len = lens[b];
        const float* __restrict__ row  = scores + (size_t)b * S * LBL;
        const int*   __restrict__ trow = tags   + (size_t)b * S;

        // t = 0
        float s0[LBL];
        #pragma unroll
        for (int j = 0; j < LBL; ++j) s0[j] = row[j];

        float alpha[LBL];
        #pragma unroll
        for (int j = 0; j < LBL; ++j) alpha[j] = sT[START_T * LBL + j] + s0[j];

        int ptag = trow[0];
        float sel0 = s0[0];
        #pragma unroll
        for (int j = 1; j < LBL; ++j) sel0 = (ptag == j) ? s0[j] : sel0;
        lab = sT[START_T * LBL + ptag] + sel0;

        for (int t = 1; t < len; ++t) {
            const float* st = row + (size_t)t * LBL;
            float s[LBL];
            #pragma unroll
            for (int j = 0; j < LBL; ++j) s[j] = st[j];

            int tg = trow[t];
            float sel = s[0];
            #pragma unroll
            for (int j = 1; j < LBL; ++j) sel = (tg == j) ? s[j] : sel;
            lab += sT[ptag * LBL + tg] + sel;
            ptag = tg;

            // alpha update: m = max_i alpha[i]; alpha'[j] = m + log(sum_i e[i]*E[i][j]) + s[j]
            float m = fmaxf(fmaxf(alpha[0], alpha[1]),
                            fmaxf(fmaxf(alpha[2], alpha[3]), alpha[4]));
            float e[LBL];
            #pragma unroll
            for (int i = 0; i < LBL; ++i) e[i] = __expf(alpha[i] - m);

            #pragma unroll
            for (int j = 0; j < LBL; ++j) {
                float d = e[0] * E[0][j];
                #pragma unroll
                for (int i = 1; i < LBL; ++i) d = fmaf(e[i], E[i][j], d);
                alpha[j] = m + __logf(d) + s[j];
            }
        }

        // end transition for labeled
        lab += sT[ptag * LBL + END_T];

        // unlabeled: logsumexp_j(alpha[j] + T[j][END])
        float la[LBL];
        #pragma unroll
        for (int j = 0; j < LBL; ++j) la[j] = alpha[j] + sT[j * LBL + END_T];
        float m = fmaxf(fmaxf(la[0], la[1]), fmaxf(fmaxf(la[2], la[3]), la[4]));
        float ss = 0.0f;
        #pragma unroll
        for (int j = 0; j < LBL; ++j) ss += __expf(la[j] - m);
        unl = m + __logf(ss);
    }

    // wave(=block) reduction: block is exactly one 64-lane wave
    #pragma unroll
    for (int off = 32; off > 0; off >>= 1) {
        unl += __shfl_down(unl, off);
        lab += __shfl_down(lab, off);
    }
    if (tid == 0) {
        atomicAdd(&out[0], unl);
        atomicAdd(&out[1], lab);
    }
}

extern "C" void kernel_launch(void* const* d_in, const int* in_sizes, int n_in,
                              void* d_out, int out_size, void* d_ws, size_t ws_size,
                              hipStream_t stream) {
    const float* scores = (const float*)d_in[0];
    const int*   lens   = (const int*)d_in[1];
    const int*   tags   = (const int*)d_in[2];
    // d_in[3] = mask (bool) — unused; recomputable from lens
    const float* trans  = (const float*)d_in[4];
    float* out = (float*)d_out;

    int B = in_sizes[1];
    int S = in_sizes[0] / (B * LBL);

    hipMemsetAsync(d_out, 0, out_size * sizeof(float), stream);

    int block = 64;
    int grid = (B + block - 1) / block;
    crf_scores_kernel<<<grid, block, 0, stream>>>(scores, lens, tags, trans, out, B, S);
}

// Round 3
// 46.062 us; speedup vs baseline: 6.9743x; 6.9743x over previous
//
#include <hip/hip_runtime.h>

#define LBL 5
#define START_T 3
#define END_T 4

// ---------------------------------------------------------------------------
// Fallback: one thread per row, serial over t (round-1 kernel, known-correct).
// ---------------------------------------------------------------------------
__global__ __launch_bounds__(64) void crf_serial_kernel(
    const float* __restrict__ scores,
    const int*   __restrict__ lens,
    const int*   __restrict__ tags,
    const float* __restrict__ trans,
    float* __restrict__ out,
    int B, int S)
{
    __shared__ float sT[LBL * LBL];
    int tid = threadIdx.x;
    if (tid < LBL * LBL) sT[tid] = trans[tid];
    __syncthreads();

    float E[LBL][LBL];
    #pragma unroll
    for (int i = 0; i < LBL; ++i) {
        #pragma unroll
        for (int j = 0; j < LBL; ++j) E[i][j] = __expf(sT[i * LBL + j]);
    }

    int b = blockIdx.x * blockDim.x + tid;
    float unl = 0.0f, lab = 0.0f;

    if (b < B) {
        int len = lens[b];
        const float* __restrict__ row  = scores + (size_t)b * S * LBL;
        const int*   __restrict__ trow = tags   + (size_t)b * S;

        float s0[LBL];
        #pragma unroll
        for (int j = 0; j < LBL; ++j) s0[j] = row[j];

        float alpha[LBL];
        #pragma unroll
        for (int j = 0; j < LBL; ++j) alpha[j] = sT[START_T * LBL + j] + s0[j];

        int ptag = trow[0];
        float sel0 = s0[0];
        #pragma unroll
        for (int j = 1; j < LBL; ++j) sel0 = (ptag == j) ? s0[j] : sel0;
        lab = sT[START_T * LBL + ptag] + sel0;

        for (int t = 1; t < len; ++t) {
            const float* st = row + (size_t)t * LBL;
            float s[LBL];
            #pragma unroll
            for (int j = 0; j < LBL; ++j) s[j] = st[j];

            int tg = trow[t];
            float sel = s[0];
            #pragma unroll
            for (int j = 1; j < LBL; ++j) sel = (tg == j) ? s[j] : sel;
            lab += sT[ptag * LBL + tg] + sel;
            ptag = tg;

            float m = fmaxf(fmaxf(alpha[0], alpha[1]),
                            fmaxf(fmaxf(alpha[2], alpha[3]), alpha[4]));
            float e[LBL];
            #pragma unroll
            for (int i = 0; i < LBL; ++i) e[i] = __expf(alpha[i] - m);

            #pragma unroll
            for (int j = 0; j < LBL; ++j) {
                float d = e[0] * E[0][j];
                #pragma unroll
                for (int i = 1; i < LBL; ++i) d = fmaf(e[i], E[i][j], d);
                alpha[j] = m + __logf(d) + s[j];
            }
        }

        lab += sT[ptag * LBL + END_T];

        float la[LBL];
        #pragma unroll
        for (int j = 0; j < LBL; ++j) la[j] = alpha[j] + sT[j * LBL + END_T];
        float m = fmaxf(fmaxf(la[0], la[1]), fmaxf(fmaxf(la[2], la[3]), la[4]));
        float ss = 0.0f;
        #pragma unroll
        for (int j = 0; j < LBL; ++j) ss += __expf(la[j] - m);
        unl = m + __logf(ss);
    }

    #pragma unroll
    for (int off = 32; off > 0; off >>= 1) {
        unl += __shfl_down(unl, off);
        lab += __shfl_down(lab, off);
    }
    if (tid == 0) {
        atomicAdd(&out[0], unl);
        atomicAdd(&out[1], lab);
    }
}

// ---------------------------------------------------------------------------
// Chunked parallel scan: one block (64 threads = 1 wave) per batch row.
// Thread c builds the 5x5 log-semiring transfer matrix of steps
// t in [1+16c, 16+16c] in scaled-exp form (Gexp row-normalized by 2^ex,
// log-scale m_i accumulated), then a short serial phase applies full-chunk
// matvecs + per-step tail from LDS. Labeled path is summed by chunk threads.
// Requires S == 1024 (64 chunks x 16 steps).
// ---------------------------------------------------------------------------
__global__ __launch_bounds__(64) void crf_chunk_kernel(
    const float* __restrict__ scores,
    const int*   __restrict__ lens,
    const int*   __restrict__ tags,
    const float* __restrict__ trans,
    float* __restrict__ out,
    int S)
{
    // padded layouts to dodge power-of-2 bank strides:
    // scores: chunk stride 82 dwords (80 data + 2 pad)  -> lane stride 82 (4-way max)
    // tags:   index t + (t>>4)                          -> lane stride 17 (free)
    // sG:     chunk stride 33 dwords (25 G + 5 m + 3)   -> write banks all distinct
    __shared__ __align__(16) float sS[64 * 82 + 2]; // 5250 dw
    __shared__ int   sTag[1024 + 64];               // 1088 dw
    __shared__ float sT[25];
    __shared__ float sE[25];
    __shared__ float sG[64 * 33];                   // 2112 dw

    const int tid = threadIdx.x;
    const int b   = blockIdx.x;
    const int len = lens[b];

    if (tid < 25) { float tv = trans[tid]; sT[tid] = tv; sE[tid] = __expf(tv); }

    const float* rowp = scores + (size_t)b * S * LBL;
    {
        const float2* row2 = (const float2*)rowp;
        int nf2 = (len * LBL + 1) >> 1;            // stage only steps < len
        for (int i = tid; i < nf2; i += 64) {
            float2 v = row2[i];
            int ch  = i / 40;                      // 40 float2 = 80 dw per chunk
            int rem = i - ch * 40;
            ((float2*)sS)[ch * 41 + rem] = v;      // 41 float2 = 82 dw stride
        }
        const int* trow = tags + (size_t)b * S;
        for (int i = tid; i < len; i += 64) sTag[i + (i >> 4)] = trow[i];
    }
    __syncthreads();

    float E[LBL][LBL];
    #pragma unroll
    for (int i = 0; i < LBL; ++i) {
        #pragma unroll
        for (int j = 0; j < LBL; ++j) E[i][j] = sE[i * LBL + j];
    }

    // chunk transfer matrix, scaled-exp form; identity to start
    float Ge[LBL][LBL];
    float mrow[LBL];
    #pragma unroll
    for (int i = 0; i < LBL; ++i) {
        mrow[i] = 0.f;
        #pragma unroll
        for (int j = 0; j < LBL; ++j) Ge[i][j] = (i == j) ? 1.f : 0.f;
    }

    float lab = 0.f;
    const int t0 = 1 + (tid << 4);

    #pragma unroll 4
    for (int tt = 0; tt < 16; ++tt) {
        int t = t0 + tt;
        if (t < S) {
            int off = (t >> 4) * 82 + (t & 15) * 5;
            float s0 = sS[off + 0], s1 = sS[off + 1], s2 = sS[off + 2],
                  s3 = sS[off + 3], s4 = sS[off + 4];
            if (t < len) {
                int tg = sTag[t + (t >> 4)];
                int pt = sTag[(t - 1) + ((t - 1) >> 4)];
                float sel = s0;
                sel = (tg == 1) ? s1 : sel;
                sel = (tg == 2) ? s2 : sel;
                sel = (tg == 3) ? s3 : sel;
                sel = (tg == 4) ? s4 : sel;
                lab += sT[pt * LBL + tg] + sel;
            }
            float es0 = __expf(s0), es1 = __expf(s1), es2 = __expf(s2),
                  es3 = __expf(s3), es4 = __expf(s4);
            #pragma unroll
            for (int i = 0; i < LBL; ++i) {
                float d0 = 0.f, d1 = 0.f, d2 = 0.f, d3 = 0.f, d4 = 0.f;
                #pragma unroll
                for (int k = 0; k < LBL; ++k) {
                    float g = Ge[i][k];
                    d0 = fmaf(g, E[k][0], d0);
                    d1 = fmaf(g, E[k][1], d1);
                    d2 = fmaf(g, E[k][2], d2);
                    d3 = fmaf(g, E[k][3], d3);
                    d4 = fmaf(g, E[k][4], d4);
                }
                d0 *= es0; d1 *= es1; d2 *= es2; d3 *= es3; d4 *= es4;
                float r = fmaxf(fmaxf(fmaxf(d0, d1), fmaxf(d2, d3)), d4);
                r = fmaxf(r, 1e-30f);                       // dead rows stay 0, m finite
                int ex = ((__float_as_int(r) >> 23) & 0xff) - 126; // frexp exponent
                Ge[i][0] = ldexpf(d0, -ex);
                Ge[i][1] = ldexpf(d1, -ex);
                Ge[i][2] = ldexpf(d2, -ex);
                Ge[i][3] = ldexpf(d3, -ex);
                Ge[i][4] = ldexpf(d4, -ex);
                mrow[i] = fmaf((float)ex, 0.69314718056f, mrow[i]);
            }
        }
    }

    {
        int gb = tid * 33;
        #pragma unroll
        for (int i = 0; i < LBL; ++i) {
            #pragma unroll
            for (int j = 0; j < LBL; ++j) sG[gb + i * LBL + j] = Ge[i][j];
            sG[gb + 25 + i] = mrow[i];
        }
    }

    // labeled: begin + end terms by lane 0, then wave-reduce
    if (tid == 0) {
        int tag0 = sTag[0];
        lab += sT[START_T * LBL + tag0] + sS[tag0];     // step 0 at dword 0
        int tl = len - 1;
        int tagE = sTag[tl + (tl >> 4)];
        lab += sT[tagE * LBL + END_T];
    }
    #pragma unroll
    for (int off = 32; off > 0; off >>= 1) lab += __shfl_down(lab, off);
    if (tid == 0) atomicAdd(out + 1, lab);

    __syncthreads();

    // serial phase: alpha0, full-chunk matvecs, per-step tail (all from LDS)
    float alpha[LBL];
    #pragma unroll
    for (int i = 0; i < LBL; ++i) alpha[i] = sT[START_T * LBL + i] + sS[i];

    const int jj = tid % 5;                 // lane's output column; lanes 0..4 feed shfl
    const int nfull = (len - 1) >> 4;

    for (int cc = 0; cc < nfull; ++cc) {
        int gb = cc * 33;
        float a0 = alpha[0] + sG[gb + 25 + 0];
        float a1 = alpha[1] + sG[gb + 25 + 1];
        float a2 = alpha[2] + sG[gb + 25 + 2];
        float a3 = alpha[3] + sG[gb + 25 + 3];
        float a4 = alpha[4] + sG[gb + 25 + 4];
        float A = fmaxf(fmaxf(fmaxf(a0, a1), fmaxf(a2, a3)), a4);
        float e0 = __expf(a0 - A), e1 = __expf(a1 - A), e2 = __expf(a2 - A),
              e3 = __expf(a3 - A), e4 = __expf(a4 - A);
        float d =       e0 * sG[gb + 0 * LBL + jj];
        d = fmaf(e1, sG[gb + 1 * LBL + jj], d);
        d = fmaf(e2, sG[gb + 2 * LBL + jj], d);
        d = fmaf(e3, sG[gb + 3 * LBL + jj], d);
        d = fmaf(e4, sG[gb + 4 * LBL + jj], d);
        float aj = A + __logf(fmaxf(d, 1e-37f));
        aj = fmaxf(aj, -1e30f);
        alpha[0] = __shfl(aj, 0);
        alpha[1] = __shfl(aj, 1);
        alpha[2] = __shfl(aj, 2);
        alpha[3] = __shfl(aj, 3);
        alpha[4] = __shfl(aj, 4);
    }

    for (int t = (nfull << 4) + 1; t < len; ++t) {
        float A = fmaxf(fmaxf(fmaxf(alpha[0], alpha[1]),
                              fmaxf(alpha[2], alpha[3])), alpha[4]);
        float e0 = __expf(alpha[0] - A), e1 = __expf(alpha[1] - A),
              e2 = __expf(alpha[2] - A), e3 = __expf(alpha[3] - A),
              e4 = __expf(alpha[4] - A);
        int off = (t >> 4) * 82 + (t & 15) * 5;
        float d =       e0 * sE[0 * LBL + jj];
        d = fmaf(e1, sE[1 * LBL + jj], d);
        d = fmaf(e2, sE[2 * LBL + jj], d);
        d = fmaf(e3, sE[3 * LBL + jj], d);
        d = fmaf(e4, sE[4 * LBL + jj], d);
        float aj = A + __logf(fmaxf(d, 1e-37f)) + sS[off + jj];
        aj = fmaxf(aj, -1e30f);
        alpha[0] = __shfl(aj, 0);
        alpha[1] = __shfl(aj, 1);
        alpha[2] = __shfl(aj, 2);
        alpha[3] = __shfl(aj, 3);
        alpha[4] = __shfl(aj, 4);
    }

    float l0 = alpha[0] + sT[0 * LBL + END_T];
    float l1 = alpha[1] + sT[1 * LBL + END_T];
    float l2 = alpha[2] + sT[2 * LBL + END_T];
    float l3 = alpha[3] + sT[3 * LBL + END_T];
    float l4 = alpha[4] + sT[4 * LBL + END_T];
    float A2 = fmaxf(fmaxf(fmaxf(l0, l1), fmaxf(l2, l3)), l4);
    float ssum = __expf(l0 - A2) + __expf(l1 - A2) + __expf(l2 - A2) +
                 __expf(l3 - A2) + __expf(l4 - A2);
    if (tid == 0) atomicAdd(out + 0, A2 + __logf(ssum));
}

extern "C" void kernel_launch(void* const* d_in, const int* in_sizes, int n_in,
                              void* d_out, int out_size, void* d_ws, size_t ws_size,
                              hipStream_t stream) {
    const float* scores = (const float*)d_in[0];
    const int*   lens   = (const int*)d_in[1];
    const int*   tags   = (const int*)d_in[2];
    // d_in[3] = mask (bool) — recomputable from lens, unused
    const float* trans  = (const float*)d_in[4];
    float* out = (float*)d_out;

    int B = in_sizes[1];
    int S = in_sizes[0] / (B * LBL);

    hipMemsetAsync(d_out, 0, out_size * sizeof(float), stream);

    if (S == 1024) {
        crf_chunk_kernel<<<B, 64, 0, stream>>>(scores, lens, tags, trans, out, S);
    } else {
        crf_serial_kernel<<<(B + 63) / 64, 64, 0, stream>>>(scores, lens, tags, trans, out, B, S);
    }
}